// Round 3
// baseline (267.517 us; speedup 1.0000x reference)
//
#include <hip/hip_runtime.h>

// ExpandEvecs: out[b][k][n][m] = sum_{j<=k} e[b][n][j] * e[b][m][j]
// B=4, C=1, N=1024, K=16. Input fp32 (proved R1: bf16-interp gave NaN).
// Output fp32 (proved R2: bf16-packed stores gave 43.2 error = misplaced-
// value + half-zero signature in an fp32 buffer). 256 MiB output,
// write-BW-bound: cumsum over k in registers, one float4 store per k.

#define BB 4
#define NN 1024
#define KK 16

__global__ __launch_bounds__(256) void ExpandEvecs_75780402970966_kernel(
    const float* __restrict__ ev,   // [B][N][K] float32
    float* __restrict__ out)        // [B][K][N][N] float32
{
    const int t  = blockIdx.x * 256 + threadIdx.x;
    const int m0 = (t & 255) << 2;           // 256 chunks of 4 m's per row
    const int n  = (t >> 8) & (NN - 1);
    const int b  = t >> 18;

    const float* eb = ev + (size_t)b * NN * KK;   // this batch's slab (64 KiB)

    float acc[4] = {0.f, 0.f, 0.f, 0.f};

    // element offset of out[b][0][n][m0]; m0 % 4 == 0 -> 16B-aligned stores
    const size_t obase = (size_t)b * KK * NN * NN + (size_t)n * NN + (size_t)m0;
    const size_t kplane = (size_t)NN * NN;

#pragma unroll
    for (int kb = 0; kb < KK / 4; ++kb) {         // k in blocks of 4
        const float4 en4 = *(const float4*)(eb + (size_t)n * KK + kb * 4);
        float4 em4[4];
#pragma unroll
        for (int v = 0; v < 4; ++v)
            em4[v] = *(const float4*)(eb + (size_t)(m0 + v) * KK + kb * 4);

        const float* enp = (const float*)&en4;
#pragma unroll
        for (int kk = 0; kk < 4; ++kk) {
            const float enk = enp[kk];
#pragma unroll
            for (int v = 0; v < 4; ++v)
                acc[v] = fmaf(((const float*)&em4[v])[kk], enk, acc[v]);

            const int k = kb * 4 + kk;
            *(float4*)(out + obase + (size_t)k * kplane) =
                make_float4(acc[0], acc[1], acc[2], acc[3]);
        }
    }
}

extern "C" void kernel_launch(void* const* d_in, const int* in_sizes, int n_in,
                              void* d_out, int out_size, void* d_ws, size_t ws_size,
                              hipStream_t stream) {
    const float* ev = (const float*)d_in[0];
    float* out = (float*)d_out;

    const int total_threads = BB * NN * (NN / 4);   // 1048576
    const int block = 256;
    const int grid = total_threads / block;          // 4096

    ExpandEvecs_75780402970966_kernel<<<grid, block, 0, stream>>>(ev, out);
}

// Round 4
// 257.695 us; speedup vs baseline: 1.0381x; 1.0381x over previous
//
#include <hip/hip_runtime.h>

// ExpandEvecs: out[b][k][n][m] = sum_{j<=k} e[b][n][j] * e[b][m][j]
// B=4, C=1, N=1024, K=16. fp32 in / fp32 out. Write-BW-bound (268 MB out,
// fill-rate ceiling 6.6 TB/s => 41 us floor).
// R4 change: each block owns 8 consecutive n-rows x all m for one b, so each
// k-step writes 32 KiB contiguous per block (was 4 KiB scattered) -> better
// HBM row-buffer locality on the store stream.

#define BB 4
#define NN 1024
#define KK 16
#define ROWS 8

__global__ __launch_bounds__(256) void ExpandEvecs_75780402970966_kernel(
    const float* __restrict__ ev,   // [B][N][K] float32
    float* __restrict__ out)        // [B][K][N][N] float32
{
    const int tid = threadIdx.x;
    const int m0  = tid << 2;                 // 256 threads x 4 m = all 1024 m
    const int grp = blockIdx.x & 127;         // n-group within b
    const int b   = blockIdx.x >> 7;
    const int n0  = grp * ROWS;

    const float* eb = ev + (size_t)b * NN * KK;   // this batch's slab (64 KiB)

    float acc[ROWS][4];
#pragma unroll
    for (int r = 0; r < ROWS; ++r)
#pragma unroll
        for (int v = 0; v < 4; ++v) acc[r][v] = 0.0f;

    const size_t kplane = (size_t)NN * NN;
    const size_t obase  = (size_t)b * KK * kplane + (size_t)n0 * NN + (size_t)m0;

#pragma unroll
    for (int kb = 0; kb < KK / 4; ++kb) {          // k in blocks of 4
        float4 em4[4];                              // this thread's 4 m-rows
#pragma unroll
        for (int v = 0; v < 4; ++v)
            em4[v] = *(const float4*)(eb + (size_t)(m0 + v) * KK + kb * 4);

        float4 en4[ROWS];                           // block-uniform -> s_load
#pragma unroll
        for (int r = 0; r < ROWS; ++r)
            en4[r] = *(const float4*)(eb + (size_t)(n0 + r) * KK + kb * 4);

#pragma unroll
        for (int kk = 0; kk < 4; ++kk) {
            const int k = kb * 4 + kk;
            float* outk = out + obase + (size_t)k * kplane;
#pragma unroll
            for (int r = 0; r < ROWS; ++r) {
                const float enk = ((const float*)&en4[r])[kk];
#pragma unroll
                for (int v = 0; v < 4; ++v)
                    acc[r][v] = fmaf(((const float*)&em4[v])[kk], enk, acc[r][v]);
                *(float4*)(outk + (size_t)r * NN) =
                    make_float4(acc[r][0], acc[r][1], acc[r][2], acc[r][3]);
            }
        }
    }
}

extern "C" void kernel_launch(void* const* d_in, const int* in_sizes, int n_in,
                              void* d_out, int out_size, void* d_ws, size_t ws_size,
                              hipStream_t stream) {
    const float* ev = (const float*)d_in[0];
    float* out = (float*)d_out;

    const int grid = BB * (NN / ROWS);   // 512 blocks, 256 threads
    ExpandEvecs_75780402970966_kernel<<<grid, 256, 0, stream>>>(ev, out);
}